// Round 9
// baseline (147.013 us; speedup 1.0000x reference)
//
#include <hip/hip_runtime.h>

#define N_NODES 50000
#define N_EDGES 800000
#define F 64
#define CHUNK 3072       // edges per partition workgroup (262 blocks > 256 CUs)
#define NWG1 ((N_EDGES + CHUNK - 1) / CHUNK)   // 261
#define NBUCK 196        // coarse buckets: dst >> 8
#define BSTRIDE 8192     // fixed per-bucket capacity (mean 4082, sigma ~64)
#define NWTILE (N_NODES / 16)   // 3125 exact
#define NSENT N_NODES    // sentinel zero-row id used for segment padding (R21)
#define SRCMID 25000     // src-range split: rows 0-24999 (3.2MB) / 25000+ (R24)

typedef __attribute__((ext_vector_type(8))) _Float16 half8;   // 16 B
typedef __attribute__((ext_vector_type(4))) float f32x4;
typedef __attribute__((ext_vector_type(8))) unsigned short ushort8v; // 16 B

// ---------- K1: partition into fixed-capacity buckets + f16 convert + W prep ----
__global__ __launch_bounds__(256) void partition_conv(
    const int*    __restrict__ src, const int* __restrict__ dst,
    const float4* __restrict__ xin,      // [N*16] float4 view of x
    half8*        __restrict__ x16,      // [(N+16)*8] f16 rows (+ sentinel row)
    unsigned short* __restrict__ h116,   // [(N+16)*64] (sentinel row zeroed here)
    const float*  __restrict__ W1, const float* __restrict__ W2,
    _Float16*     __restrict__ Wt1, _Float16* __restrict__ Wt2,
    unsigned*     __restrict__ bcur,     // [256] zeroed cursors
    unsigned*     __restrict__ ebuf) {   // [NBUCK*BSTRIDE] strided buckets
  int t = threadIdx.x, b = blockIdx.x;
  if (b == NWG1) {                       // W prep block
    for (int i = t; i < 64 * 128; i += 256) {
      int n = i >> 7, k = i & 127;       // Wt[n][k] = W[k][n]
      Wt1[i] = (_Float16)W1[k * 64 + n];
      Wt2[i] = (_Float16)W2[k * 64 + n];
    }
    // zero sentinel rows (gathered by pad ids; contribute exact +0.0)
    if (t < 32) ((unsigned*)(x16 + (size_t)NSENT * 8))[t] = 0;            // 128 B
    if (t >= 64 && t < 96) ((unsigned*)h116)[(size_t)NSENT * 32 + (t - 64)] = 0;
    return;
  }
  __shared__ int hist[256], lscan[256], lcur[256], gbase[256];
  __shared__ unsigned stage[CHUNK];      // 12 KB
  hist[t] = 0; __syncthreads();
  int e0 = b * CHUNK;
  int cnt = N_EDGES - e0; if (cnt > CHUNK) cnt = CHUNK;
  for (int i = t; i < cnt; i += 256) atomicAdd(&hist[dst[e0 + i] >> 8], 1);

  // f32 -> f16 feature conversion, grid-stride
  const int TOT = N_NODES * F / 8;
  for (int i = b * 256 + t; i < TOT; i += NWG1 * 256) {
    float4 a = xin[i * 2], c = xin[i * 2 + 1];
    half8 hh;
    hh[0] = (_Float16)a.x; hh[1] = (_Float16)a.y;
    hh[2] = (_Float16)a.z; hh[3] = (_Float16)a.w;
    hh[4] = (_Float16)c.x; hh[5] = (_Float16)c.y;
    hh[6] = (_Float16)c.z; hh[7] = (_Float16)c.w;
    x16[i] = hh;
  }
  __syncthreads();

  int v = hist[t];
  lscan[t] = v; __syncthreads();
  for (int off = 1; off < 256; off <<= 1) {
    int a = (t >= off) ? lscan[t - off] : 0;
    __syncthreads();
    lscan[t] += a;
    __syncthreads();
  }
  lscan[t] -= v;                         // exclusive local scan
  lcur[t] = lscan[t];
  if (v > 0) gbase[t] = (int)atomicAdd(&bcur[t], (unsigned)v);  // in-bucket base
  __syncthreads();

  for (int i = t; i < cnt; i += 256) {
    int d = dst[e0 + i], s = src[e0 + i];
    int bb = d >> 8;
    int p = atomicAdd(&lcur[bb], 1);
    stage[p] = ((unsigned)bb << 24) | ((unsigned)(d & 255) << 16) | (unsigned)s;
  }
  __syncthreads();
  for (int i = t; i < cnt; i += 256) {
    unsigned e = stage[i];
    int bb = e >> 24;
    ebuf[bb * BSTRIDE + gbase[bb] + (i - lscan[bb])] = e;   // coalesced runs
  }
}

// ---------- K2: per-bucket counting sort, 256 bins = node x src-half (R24) ----
// Each node's segment is split into lo-src (<SRCMID) and hi-src sub-segments,
// each sentinel-padded to 8. The gather kernel runs pass-lo then pass-hi so
// each pass's hot table set is 3.2MB -> fits a 4MB per-XCD L2 (kills the
// ~40% L2 miss rate on the 6.4MB table; R5 measured 24MB misses/layer at
// ~2TB/s = the latency floor all ILP/TLP probes couldn't move).
// deg[n] packs dlo | dhi<<16. Within-sub-segment order was already atomic-
// nondeterministic; absmax is storage-quantization-dominated (stable 2^-6).
// Capacity: 2041 real + 256 bins * ~3.5 pad ~= 2940 +- ~60 < 4096. srt 8KB.
__global__ __launch_bounds__(256) void bucket_sort(
    const unsigned* __restrict__ ebuf, const unsigned* __restrict__ bcur,
    unsigned short* __restrict__ edge_src, int* __restrict__ row_start,
    int* __restrict__ deg, unsigned char* __restrict__ perm) {
  __shared__ int lhist[256], lscan[256], lcur[256];
  __shared__ unsigned short srt[BSTRIDE / 2];    // 8 KB
  int B = blockIdx.x, t = threadIdx.x;
  int b = B >> 1, h = B & 1;
  int s0 = b * BSTRIDE;
  int cnt = (int)bcur[b];

  lhist[t] = 0;
  __syncthreads();
  for (int i = t; i < cnt; i += 256) {
    unsigned e = ebuf[s0 + i];
    int obin = (int)((e >> 16) & 255);
    if ((obin >> 7) == h) {
      int bin = ((obin & 127) << 1) | ((e & 0xFFFFu) >= (unsigned)SRCMID);
      atomicAdd(&lhist[bin], 1);
    }
  }
  __syncthreads();

  int v  = lhist[t];
  int pv = (v + 7) & ~7;                 // padded sub-segment size (8-aligned)
  lscan[t] = pv;
  __syncthreads();
  for (int off = 1; off < 256; off <<= 1) {
    int a = (t >= off) ? lscan[t - off] : 0;
    __syncthreads();
    lscan[t] += a;
    __syncthreads();
  }
  lscan[t] -= pv;                        // exclusive padded scan
  lcur[t] = lscan[t];
  __syncthreads();

  int total_p = lscan[255] + ((lhist[255] + 7) & ~7);   // padded half size
  int base    = h * (BSTRIDE / 2);                      // fixed half offset

  for (int i = t; i < cnt; i += 256) {
    unsigned e = ebuf[s0 + i];
    int obin = (int)((e >> 16) & 255);
    if ((obin >> 7) == h) {
      int bin = ((obin & 127) << 1) | ((e & 0xFFFFu) >= (unsigned)SRCMID);
      int p = atomicAdd(&lcur[bin], 1);
      srt[p] = (unsigned short)(e & 0xFFFFu);
    }
  }
  __syncthreads();
  {                                       // sentinel-fill pad slots (zero row)
    int p0 = lscan[t];
    for (int j = v; j < pv; ++j) srt[p0 + j] = (unsigned short)NSENT;
  }
  __syncthreads();

  for (int i = t; i < total_p; i += 256) edge_src[s0 + base + i] = srt[i];  // 2B coalesced

  if (t < 128) {
    int n = b * 256 + h * 128 + t;
    int vlo = lhist[2 * t], vhi = lhist[2 * t + 1];
    if (n < N_NODES) {
      row_start[n] = s0 + base + lscan[2 * t];   // lo start; hi = +pad8(vlo)
      deg[n] = vlo | (vhi << 16);
    }
    // degree-rank permutation within this node's 32-group (by total degree)
    int g0 = t & ~31, me = t & 31, vt = vlo + vhi;
    int rank = 0;
    #pragma unroll 8
    for (int j = 0; j < 32; ++j) {
      int dj = lhist[2 * (g0 + j)] + lhist[2 * (g0 + j) + 1];
      rank += (dj < vt) || (dj == vt && j < me);
    }
    perm[b * 256 + h * 128 + g0 + rank] = (unsigned char)me;
  }
}

// 8-wide unconditional gather batch loop (sentinel-padded, id prefetch)
#define GATHER_LOOP(IDP, NB)                                        \
  {                                                                 \
    const ushort8v* idp_ = (IDP);                                   \
    int nb_ = (NB);                                                 \
    ushort8v iv = idp_[0];                                          \
    for (int b_ = 0; b_ < nb_; ++b_) {                              \
      half8 h0 = feat16[(size_t)iv[0] * 8 + q];                     \
      half8 h1 = feat16[(size_t)iv[1] * 8 + q];                     \
      half8 h2 = feat16[(size_t)iv[2] * 8 + q];                     \
      half8 h3 = feat16[(size_t)iv[3] * 8 + q];                     \
      half8 h4 = feat16[(size_t)iv[4] * 8 + q];                     \
      half8 h5 = feat16[(size_t)iv[5] * 8 + q];                     \
      half8 h6 = feat16[(size_t)iv[6] * 8 + q];                     \
      half8 h7 = feat16[(size_t)iv[7] * 8 + q];                     \
      ushort8v nv;                                                  \
      bool more = (b_ + 1 < nb_);                                   \
      if (more) nv = idp_[b_ + 1];                                  \
      acc8 += h0; acc8 += h1; acc8 += h2; acc8 += h3;               \
      acc8 += h4; acc8 += h5; acc8 += h6; acc8 += h7;               \
      if (more) iv = nv;                                            \
    }                                                               \
  }

// ---------- fused layer: octet-per-node aggregate -> LDS -> MFMA linear ----------
// Block = 4 waves = 32 nodes = 2 MFMA tiles.
// Phase 1 (R24): two-pass gather (lo-src rows then hi-src rows); each pass's
//   working set is a 3.2MB half-table -> per-XCD-L2 resident. Degree-ranked
//   octet assignment (R23) keeps wave trip ~= mean. Per-column accumulation
//   within each sub-segment preserves the (already nondeterministic) segment
//   order; pad adds are exact +0.0.
// Phase 2: unchanged; lmean slot = original local index, tiles intact.
__global__ __launch_bounds__(256) void sage_layer_fused(
    const half8*    __restrict__ feat16,    // [N+16,8] gather source (= self16)
    const _Float16* __restrict__ self16,    // [N,64]
    const int*      __restrict__ row_start,
    const int*      __restrict__ deg,       // packed dlo | dhi<<16
    const unsigned short* __restrict__ edge_src,
    const unsigned char* __restrict__ perm, // [~N] degree-rank perm (32-groups)
    const _Float16* __restrict__ Wt,        // [64,128]  Wt[n][k] = W[k][n]
    const float*    __restrict__ bias,      // [64]
    float*          __restrict__ outf,      // [N,64] f32 or null
    unsigned short* __restrict__ out16,     // [N,64] f16 or null
    int do_relu) {
  __shared__ _Float16 lmean[32 * 72];       // node stride 72 halves, 4.6 KB
  int t = threadIdx.x;
  int w = t >> 6, lane = t & 63;

  // ---- phase 1: aggregate 8 nodes per wave (degree-ranked, two passes) ----
  {
    int o = lane >> 3, q = lane & 7;
    int ln = (int)perm[blockIdx.x * 32 + w * 8 + o];   // local node 0..31
    int n = blockIdx.x * 32 + ln;
    if (n < N_NODES) {
      int start = row_start[n];            // multiple of 8 (16B-aligned)
      int dpack = deg[n];
      int dl = dpack & 0xFFFF, dh = dpack >> 16;
      int d  = dl + dh;
      half8 acc8 = (half8){0, 0, 0, 0, 0, 0, 0, 0};
      if (dl > 0) GATHER_LOOP((const ushort8v*)(edge_src + start), (dl + 7) >> 3);
      if (dh > 0) GATHER_LOOP((const ushort8v*)(edge_src + start + ((dl + 7) & ~7)),
                              (dh + 7) >> 3);
      float inv = (d > 0) ? 1.0f / (float)d : 0.0f;
      half8 hm;
      #pragma unroll
      for (int k = 0; k < 8; ++k) hm[k] = (_Float16)((float)acc8[k] * inv);
      *(half8*)&lmean[ln * 72 + q * 8] = hm;
    }
  }
  __syncthreads();

  // ---- phase 2: MFMA linear; wave w does nt-half (w&1) of tile (w>>1) ----
  int tile = w >> 1;
  int wt = blockIdx.x * 2 + tile;
  if (wt >= NWTILE) return;
  int m = lane & 15, quad = lane >> 4;
  size_t arow = (size_t)(wt * 16 + m) * 64 + quad * 8;
  half8 a0 = *(const half8*)(self16 + arow);
  half8 a1 = *(const half8*)(self16 + arow + 32);
  int ln = tile * 16 + m;                   // local node 0..31
  half8 a2 = *(const half8*)&lmean[ln * 72 + quad * 8];
  half8 a3 = *(const half8*)&lmean[ln * 72 + quad * 8 + 32];

  int nt0 = (w & 1) * 2;                    // 0 or 2
  #pragma unroll
  for (int i = 0; i < 2; ++i) {
    int nt = nt0 + i;
    float bv = bias[nt * 16 + m];           // col = lane&15
    f32x4 acc = (f32x4){bv, bv, bv, bv};
    const _Float16* wrow = Wt + (size_t)(nt * 16 + m) * 128 + quad * 8;
    half8 b0 = *(const half8*)(wrow);
    half8 b1 = *(const half8*)(wrow + 32);
    half8 b2 = *(const half8*)(wrow + 64);
    half8 b3 = *(const half8*)(wrow + 96);
    acc = __builtin_amdgcn_mfma_f32_16x16x32_f16(a0, b0, acc, 0, 0, 0);
    acc = __builtin_amdgcn_mfma_f32_16x16x32_f16(a1, b1, acc, 0, 0, 0);
    acc = __builtin_amdgcn_mfma_f32_16x16x32_f16(a2, b2, acc, 0, 0, 0);
    acc = __builtin_amdgcn_mfma_f32_16x16x32_f16(a3, b3, acc, 0, 0, 0);
    #pragma unroll
    for (int r = 0; r < 4; ++r) {
      size_t off = (size_t)(wt * 16 + quad * 4 + r) * 64 + nt * 16 + m;
      float v = acc[r];
      if (do_relu) v = fmaxf(v, 0.0f);
      if (outf)  outf[off] = v;
      if (out16) { _Float16 hv = (_Float16)v; out16[off] = *(unsigned short*)&hv; }
    }
  }
}

extern "C" void kernel_launch(void* const* d_in, const int* in_sizes, int n_in,
                              void* d_out, int out_size, void* d_ws, size_t ws_size,
                              hipStream_t stream) {
  const float* x  = (const float*)d_in[0];
  const int*   ei = (const int*)d_in[1];   // [2,E]: row 0 = src, row 1 = dst
  const float* W1 = (const float*)d_in[2];
  const float* b1 = (const float*)d_in[3];
  const float* W2 = (const float*)d_in[4];
  const float* b2 = (const float*)d_in[5];
  float* out = (float*)d_out;

  const int* src = ei;
  const int* dst = ei + N_EDGES;

  // ws layout (int offsets), all 16B-aligned:
  //   bcur@0[256] | deg@256[50048] | row_start@50304[50048] |
  //   edge_src@100352[802816] | ebuf@903168[1605632] |
  //   x16@2508800[1600512 (+sentinel)] | h116@4109312[1600512] |
  //   Wt1@5709824[4096] | Wt2@5713920[4096] | perm@5718016[12544 bytes-as-ints]
  //   total 5,730,560 ints = 22.9 MB
  int* wsi       = (int*)d_ws;
  unsigned* bcur = (unsigned*)wsi;
  int* deg       = wsi + 256;
  int* row_start = wsi + 50304;
  unsigned short* edge_src = (unsigned short*)(wsi + 100352);
  unsigned* ebuf = (unsigned*)(wsi + 903168);
  half8* x16     = (half8*)(wsi + 2508800);
  unsigned short* h116 = (unsigned short*)(wsi + 4109312);
  _Float16* Wt1  = (_Float16*)(wsi + 5709824);
  _Float16* Wt2  = (_Float16*)(wsi + 5713920);
  unsigned char* perm = (unsigned char*)(wsi + 5718016);

  hipMemsetAsync(bcur, 0, 256 * sizeof(unsigned), stream);

  dim3 blk(256);
  partition_conv<<<NWG1 + 1, blk, 0, stream>>>(
      src, dst, (const float4*)x, x16, h116, W1, W2, Wt1, Wt2, bcur, ebuf);
  bucket_sort<<<NBUCK * 2, blk, 0, stream>>>(ebuf, bcur, edge_src, row_start,
                                             deg, perm);

  dim3 grd_fused((N_NODES + 31) / 32);   // 1563 blocks = 3126 tiles >= 3125

  // Layer 1: h1 = relu([x||mean]W1+b1), kept only as f16
  sage_layer_fused<<<grd_fused, blk, 0, stream>>>(
      x16, (const _Float16*)x16, row_start, deg, edge_src, perm,
      Wt1, b1, nullptr, h116, 1);
  // Layer 2: out = [h1||mean]W2+b2 (f32)
  sage_layer_fused<<<grd_fused, blk, 0, stream>>>(
      (const half8*)h116, (const _Float16*)h116, row_start, deg, edge_src, perm,
      Wt2, b2, out, nullptr, 0);
}